// Round 2
// baseline (1140.256 us; speedup 1.0000x reference)
//
#include <hip/hip_runtime.h>
#include <stdint.h>

// Problem constants (B=2, D_MODEL=256, C=64, T=1024, H=8, F=32)
// All inputs fp32 (per reference dtypes), output fp32.
// Internal intermediates (folded weights, qkv, att) are bf16.
#define D_MODEL 256
#define TDIM    1024
#define NHEADS  8
#define FDIM    32
#define P_LEN   65536      // C*T positions per batch
#define K3      768        // 3*D_MODEL

using u16 = unsigned short;

__device__ __forceinline__ float b2f(u16 u) {
    union { float f; uint32_t i; } v; v.i = ((uint32_t)u) << 16; return v.f;
}
__device__ __forceinline__ u16 f2b(float f) {
    union { float f; uint32_t i; } v; v.f = f;
    uint32_t i = v.i;
    uint32_t r = i + 0x7fffu + ((i >> 16) & 1u);   // RNE
    return (u16)(r >> 16);
}

// dtype-generic load/store helpers
__device__ __forceinline__ float4 ld4(const float* p) { return *(const float4*)p; }
__device__ __forceinline__ float4 ld4(const u16* p) {
    ushort4 u = *(const ushort4*)p;
    return make_float4(b2f(u.x), b2f(u.y), b2f(u.z), b2f(u.w));
}
__device__ __forceinline__ void st4(float* p, float4 v) { *(float4*)p = v; }
__device__ __forceinline__ void st4(u16* p, float4 v) {
    *(ushort4*)p = make_ushort4(f2b(v.x), f2b(v.y), f2b(v.z), f2b(v.w));
}

// ---------------------------------------------------------------------------
// 1) InstanceNorm stats: one block per (b,d) row of 65536 fp32 elements.
// ---------------------------------------------------------------------------
__global__ __launch_bounds__(256) void stats_kernel(const float* __restrict__ x,
                                                    float* __restrict__ mu,
                                                    float* __restrict__ rstd) {
    int bd = blockIdx.x;                       // 0..511
    const float* row = x + (size_t)bd * P_LEN;
    int tid = threadIdx.x;
    float s = 0.f, sq = 0.f;
    for (int i = 0; i < P_LEN / (256 * 4); ++i) {     // 64 iters, float4 coalesced
        int idx = (i * 256 + tid) * 4;
        float4 u = *(const float4*)(row + idx);
        s += u.x + u.y + u.z + u.w;
        sq += u.x * u.x + u.y * u.y + u.z * u.z + u.w * u.w;
    }
    for (int off = 32; off; off >>= 1) { s += __shfl_down(s, off); sq += __shfl_down(sq, off); }
    __shared__ float rs[4], rq[4];
    if ((tid & 63) == 0) { rs[tid >> 6] = s; rq[tid >> 6] = sq; }
    __syncthreads();
    if (tid == 0) {
        float S = rs[0] + rs[1] + rs[2] + rs[3];
        float Q = rq[0] + rq[1] + rq[2] + rq[3];
        float m = S * (1.f / 65536.f);
        float var = Q * (1.f / 65536.f) - m * m;
        mu[bd] = m;
        rstd[bd] = rsqrtf(var + 1e-5f);
    }
}

// ---------------------------------------------------------------------------
// 2) Fold norm into QKV weights: Wp[b][e][d] = in_w[e][d]*rstd[b][d] (bf16),
//    bprime[b][e] = in_b[e] - sum_d in_w[e][d]*mu[b][d]*rstd[b][d]  (fp32).
//    One block per (b,e); thread = d.
// ---------------------------------------------------------------------------
__global__ __launch_bounds__(256) void fold_kernel(const float* __restrict__ in_w,
                                                   const float* __restrict__ in_b,
                                                   const float* __restrict__ mu,
                                                   const float* __restrict__ rstd,
                                                   u16* __restrict__ Wp,
                                                   float* __restrict__ bprime) {
    int bid = blockIdx.x;              // b*768 + e
    int b = bid / K3, e = bid % K3;
    int d = threadIdx.x;
    float w = in_w[e * D_MODEL + d];
    float r = rstd[b * D_MODEL + d];
    float m = mu[b * D_MODEL + d];
    Wp[(size_t)bid * D_MODEL + d] = f2b(w * r);
    float contrib = w * r * m;
    for (int off = 32; off; off >>= 1) contrib += __shfl_down(contrib, off);
    __shared__ float rr[4];
    if ((d & 63) == 0) rr[d >> 6] = contrib;
    __syncthreads();
    if (d == 0) bprime[bid] = in_b[e] - (rr[0] + rr[1] + rr[2] + rr[3]);
}

// convert out_w (256x256 fp32) to bf16
__global__ void cvt_w(const float* __restrict__ w, u16* __restrict__ o) {
    int i = blockIdx.x * 256 + threadIdx.x;
    o[i] = f2b(w[i]);
}

// ---------------------------------------------------------------------------
// 3) GEMM: C[M x 65536] = A[M x 256](bf16) * B[256 x 65536](BT) + bias
//    (+ fp32 residual). fp32 compute. 128x128 tile, 8x8 micro, BK=8, 256 thr.
// ---------------------------------------------------------------------------
template <bool RESID, typename BT, typename OT>
__global__ __launch_bounds__(256) void gemm_k(const u16* __restrict__ A,
                                              const BT* __restrict__ B,
                                              const float* __restrict__ bias,
                                              const float* __restrict__ resid,
                                              OT* __restrict__ Cout) {
    __shared__ float As[8][132];   // [k][m], padded
    __shared__ float Bs[8][128];   // [k][n]
    int tid = threadIdx.x;
    int m0 = blockIdx.y * 128;
    int p0 = blockIdx.x * 128;

    int ar = tid >> 1;             // A row in tile (0..127)
    int ac = (tid & 1) * 4;        // A k-offset (0 or 4)
    int bkk = tid >> 5;            // B k row (0..7)
    int bcol = (tid & 31) * 4;     // B col (0..124)

    float acc[8][8];
#pragma unroll
    for (int i = 0; i < 8; i++)
#pragma unroll
        for (int j = 0; j < 8; j++) acc[i][j] = 0.f;

    int ty = tid >> 4, tx = tid & 15;
    int i0 = ty * 8, j0 = tx * 8;

    for (int kt = 0; kt < 32; ++kt) {
        int k0 = kt * 8;
        float4 av = ld4(A + (size_t)(m0 + ar) * D_MODEL + k0 + ac);
        float4 bv = ld4(B + (size_t)(k0 + bkk) * P_LEN + p0 + bcol);
        __syncthreads();
        As[ac + 0][ar] = av.x;
        As[ac + 1][ar] = av.y;
        As[ac + 2][ar] = av.z;
        As[ac + 3][ar] = av.w;
        *(float4*)&Bs[bkk][bcol] = bv;
        __syncthreads();
#pragma unroll
        for (int kk = 0; kk < 8; ++kk) {
            const float4* a4 = (const float4*)&As[kk][i0];
            const float4* b4 = (const float4*)&Bs[kk][j0];
            float4 a0 = a4[0], a1 = a4[1];
            float4 c0 = b4[0], c1 = b4[1];
            float a[8] = {a0.x, a0.y, a0.z, a0.w, a1.x, a1.y, a1.z, a1.w};
            float bb[8] = {c0.x, c0.y, c0.z, c0.w, c1.x, c1.y, c1.z, c1.w};
#pragma unroll
            for (int i = 0; i < 8; i++)
#pragma unroll
                for (int j = 0; j < 8; j++) acc[i][j] += a[i] * bb[j];
        }
    }

#pragma unroll
    for (int i = 0; i < 8; i++) {
        int m = m0 + i0 + i;
        float bv = bias[m];
        size_t rowoff = (size_t)m * P_LEN + p0 + j0;
        float4 v0 = make_float4(acc[i][0] + bv, acc[i][1] + bv, acc[i][2] + bv, acc[i][3] + bv);
        float4 v1 = make_float4(acc[i][4] + bv, acc[i][5] + bv, acc[i][6] + bv, acc[i][7] + bv);
        if (RESID) {
            float4 r0 = *(const float4*)(resid + rowoff);
            float4 r1 = *(const float4*)(resid + rowoff + 4);
            v0.x += r0.x; v0.y += r0.y; v0.z += r0.z; v0.w += r0.w;
            v1.x += r1.x; v1.y += r1.y; v1.z += r1.z; v1.w += r1.w;
        }
        st4(Cout + rowoff, v0);
        st4(Cout + rowoff + 4, v1);
    }
}

// ---------------------------------------------------------------------------
// 4) Attention per (c,h) for one batch. qkv layout [768][65536] (bf16).
//    k-softmax over t (+/T folded), ctx=32x32 (+q-scale folded),
//    per-column q-softmax, out = ctx^T * q_sm.  Output att [256][65536] bf16.
// ---------------------------------------------------------------------------
__global__ __launch_bounds__(256) void attn_k(const u16* __restrict__ qkv,
                                              u16* __restrict__ att) {
    int bid = blockIdx.x;          // 0..511
    int c = bid >> 3, h = bid & 7;
    int tid = threadIdx.x;
    size_t colbase = (size_t)c * TDIM;
    const u16* qb = qkv + (size_t)(h * FDIM) * P_LEN + colbase;
    const u16* kb = qkv + (size_t)(D_MODEL + h * FDIM) * P_LEN + colbase;
    const u16* vb = qkv + (size_t)(2 * D_MODEL + h * FDIM) * P_LEN + colbase;

    __shared__ float kmax[32], kinv[32];
    __shared__ float ekt[32][65];     // exp-normalized k tile [f][t_local]
    __shared__ float vt[64][36];      // v tile transposed [t_local][f]
    __shared__ float ctxs[32][36];    // ctx [kd][vd] * scale

    int row = tid >> 3, g = tid & 7;
    const u16* krow = kb + (size_t)row * P_LEN;

    // pass 1: row max of k
    float m = -1e30f;
    for (int i = 0; i < 32; ++i) {
        ushort4 u = *(const ushort4*)(krow + g * 4 + i * 32);
        m = fmaxf(m, fmaxf(fmaxf(b2f(u.x), b2f(u.y)), fmaxf(b2f(u.z), b2f(u.w))));
    }
    for (int off = 4; off; off >>= 1) m = fmaxf(m, __shfl_down(m, off, 8));
    if (g == 0) kmax[row] = m;
    __syncthreads();
    // pass 2: row sum of exp
    float rm = kmax[row];
    float s = 0.f;
    for (int i = 0; i < 32; ++i) {
        ushort4 u = *(const ushort4*)(krow + g * 4 + i * 32);
        s += __expf(b2f(u.x) - rm) + __expf(b2f(u.y) - rm) +
             __expf(b2f(u.z) - rm) + __expf(b2f(u.w) - rm);
    }
    for (int off = 4; off; off >>= 1) s += __shfl_down(s, off, 8);
    if (g == 0) kinv[row] = 1.f / (s * (float)TDIM);   // /T folded here
    __syncthreads();

    float mymax = kmax[row];
    float myinv = kinv[row];
    const u16* vrow = vb + (size_t)row * P_LEN;

    // ctx accumulation: thread owns ctx[kd][vg*4 .. vg*4+3]
    int kd = tid >> 3, vg = tid & 7;
    float cacc[4] = {0.f, 0.f, 0.f, 0.f};
    for (int tile = 0; tile < 16; ++tile) {
        int t0 = tile * 64;
        int col = g * 8;
        ushort4 u1 = *(const ushort4*)(krow + t0 + col);
        ushort4 u2 = *(const ushort4*)(krow + t0 + col + 4);
        ushort4 w1 = *(const ushort4*)(vrow + t0 + col);
        ushort4 w2 = *(const ushort4*)(vrow + t0 + col + 4);
        __syncthreads();
        ekt[row][col + 0] = __expf(b2f(u1.x) - mymax) * myinv;
        ekt[row][col + 1] = __expf(b2f(u1.y) - mymax) * myinv;
        ekt[row][col + 2] = __expf(b2f(u1.z) - mymax) * myinv;
        ekt[row][col + 3] = __expf(b2f(u1.w) - mymax) * myinv;
        ekt[row][col + 4] = __expf(b2f(u2.x) - mymax) * myinv;
        ekt[row][col + 5] = __expf(b2f(u2.y) - mymax) * myinv;
        ekt[row][col + 6] = __expf(b2f(u2.z) - mymax) * myinv;
        ekt[row][col + 7] = __expf(b2f(u2.w) - mymax) * myinv;
        vt[col + 0][row] = b2f(w1.x);
        vt[col + 1][row] = b2f(w1.y);
        vt[col + 2][row] = b2f(w1.z);
        vt[col + 3][row] = b2f(w1.w);
        vt[col + 4][row] = b2f(w2.x);
        vt[col + 5][row] = b2f(w2.y);
        vt[col + 6][row] = b2f(w2.z);
        vt[col + 7][row] = b2f(w2.w);
        __syncthreads();
#pragma unroll 16
        for (int t = 0; t < 64; ++t) {
            float e = ekt[kd][t];
            float4 v4 = *(const float4*)&vt[t][vg * 4];
            cacc[0] += e * v4.x;
            cacc[1] += e * v4.y;
            cacc[2] += e * v4.z;
            cacc[3] += e * v4.w;
        }
    }
    __syncthreads();
    const float scale = 0.17677669529663687f;   // 1/sqrt(32)
    ctxs[kd][vg * 4 + 0] = cacc[0] * scale;
    ctxs[kd][vg * 4 + 1] = cacc[1] * scale;
    ctxs[kd][vg * 4 + 2] = cacc[2] * scale;
    ctxs[kd][vg * 4 + 3] = cacc[3] * scale;
    __syncthreads();

    // out = ctx^T * softmax_f(q): each thread handles 4 t-columns (2 pairs)
    for (int pair = 0; pair < 2; ++pair) {
        int t1 = tid + pair * 512;
        int t2 = t1 + 256;
        float pa[32], pb[32];
        float ma = -1e30f, mb = -1e30f;
#pragma unroll
        for (int f = 0; f < 32; ++f) {
            pa[f] = b2f(qb[(size_t)f * P_LEN + t1]);
            pb[f] = b2f(qb[(size_t)f * P_LEN + t2]);
            ma = fmaxf(ma, pa[f]);
            mb = fmaxf(mb, pb[f]);
        }
        float sa = 0.f, sb = 0.f;
#pragma unroll
        for (int f = 0; f < 32; ++f) {
            pa[f] = __expf(pa[f] - ma); sa += pa[f];
            pb[f] = __expf(pb[f] - mb); sb += pb[f];
        }
        float ia = 1.f / sa, ib = 1.f / sb;
#pragma unroll
        for (int f = 0; f < 32; ++f) { pa[f] *= ia; pb[f] *= ib; }

        for (int vg2 = 0; vg2 < 8; ++vg2) {
            float4 a1 = {0.f, 0.f, 0.f, 0.f}, a2 = {0.f, 0.f, 0.f, 0.f};
#pragma unroll
            for (int kd2 = 0; kd2 < 32; ++kd2) {
                float4 c4 = *(const float4*)&ctxs[kd2][vg2 * 4];
                a1.x += pa[kd2] * c4.x; a1.y += pa[kd2] * c4.y;
                a1.z += pa[kd2] * c4.z; a1.w += pa[kd2] * c4.w;
                a2.x += pb[kd2] * c4.x; a2.y += pb[kd2] * c4.y;
                a2.z += pb[kd2] * c4.z; a2.w += pb[kd2] * c4.w;
            }
            size_t r0 = (size_t)(h * FDIM + vg2 * 4);
            att[(r0 + 0) * P_LEN + colbase + t1] = f2b(a1.x);
            att[(r0 + 1) * P_LEN + colbase + t1] = f2b(a1.y);
            att[(r0 + 2) * P_LEN + colbase + t1] = f2b(a1.z);
            att[(r0 + 3) * P_LEN + colbase + t1] = f2b(a1.w);
            att[(r0 + 0) * P_LEN + colbase + t2] = f2b(a2.x);
            att[(r0 + 1) * P_LEN + colbase + t2] = f2b(a2.y);
            att[(r0 + 2) * P_LEN + colbase + t2] = f2b(a2.z);
            att[(r0 + 3) * P_LEN + colbase + t2] = f2b(a2.w);
        }
    }
}

// ---------------------------------------------------------------------------
// Workspace layout (bytes):
//   mu      [512]  f32            @ 0
//   rstd    [512]  f32            @ 2048
//   Wp      [1536*256] bf16       @ 4096        (786432)
//   bprime  [1536] f32            @ 790528      (6144)
//   Wp2     [256*256]  bf16       @ 796672      (131072)
//   qkv_b   [768*65536] bf16      @ 927744      (100663296)  -- reused per batch
//   att_b   [256*65536] bf16      @ 101591040   (33554432)   -- reused per batch
// total = 135145472 bytes (~135 MB)
// ---------------------------------------------------------------------------
extern "C" void kernel_launch(void* const* d_in, const int* in_sizes, int n_in,
                              void* d_out, int out_size, void* d_ws, size_t ws_size,
                              hipStream_t stream) {
    const float* x     = (const float*)d_in[0];
    const float* in_w  = (const float*)d_in[1];
    const float* in_b  = (const float*)d_in[2];
    const float* out_w = (const float*)d_in[3];
    const float* out_b = (const float*)d_in[4];
    float* out = (float*)d_out;

    char* ws = (char*)d_ws;
    float* mu     = (float*)(ws);
    float* rstd   = (float*)(ws + 2048);
    u16*   Wp     = (u16*)(ws + 4096);
    float* bprime = (float*)(ws + 790528);
    u16*   Wp2    = (u16*)(ws + 796672);
    u16*   qkvb   = (u16*)(ws + 927744);
    u16*   attb   = (u16*)(ws + 927744 + 100663296);

    stats_kernel<<<512, 256, 0, stream>>>(x, mu, rstd);
    fold_kernel<<<1536, 256, 0, stream>>>(in_w, in_b, mu, rstd, Wp, bprime);
    cvt_w<<<256, 256, 0, stream>>>(out_w, Wp2);

    for (int b = 0; b < 2; ++b) {
        gemm_k<false, float, u16><<<dim3(512, 6, 1), 256, 0, stream>>>(
            Wp + (size_t)b * K3 * D_MODEL,
            x + (size_t)b * D_MODEL * P_LEN,
            bprime + b * K3, nullptr, qkvb);
        attn_k<<<512, 256, 0, stream>>>(qkvb, attb);
        gemm_k<true, u16, float><<<dim3(512, 2, 1), 256, 0, stream>>>(
            Wp2,
            attb,
            out_b,
            x + (size_t)b * D_MODEL * P_LEN,
            out + (size_t)b * D_MODEL * P_LEN);
    }
}

// Round 3
// 647.684 us; speedup vs baseline: 1.7605x; 1.7605x over previous
//
#include <hip/hip_runtime.h>
#include <stdint.h>

// Problem constants (B=2, D_MODEL=256, C=64, T=1024, H=8, F=32)
// Inputs fp32, output fp32. Intermediates bf16. GEMMs on MFMA bf16.
#define D_MODEL 256
#define TDIM    1024
#define NHEADS  8
#define FDIM    32
#define P_LEN   65536      // C*T positions per batch
#define K3      768        // 3*D_MODEL
#define BK      64         // K-tile per LDS stage

using u16 = unsigned short;

typedef __bf16 bf16x8 __attribute__((ext_vector_type(8)));
typedef float  floatx4 __attribute__((ext_vector_type(4)));

__device__ __forceinline__ float b2f(u16 u) {
    union { float f; uint32_t i; } v; v.i = ((uint32_t)u) << 16; return v.f;
}
__device__ __forceinline__ u16 f2b(float f) {
    union { float f; uint32_t i; } v; v.f = f;
    uint32_t i = v.i;
    uint32_t r = i + 0x7fffu + ((i >> 16) & 1u);   // RNE
    return (u16)(r >> 16);
}

// async global->LDS, 16B per lane; lds base must be wave-uniform, lane i
// lands at base + i*16 (guide §5 / m97 / m104).
__device__ __forceinline__ void gload_lds16(const u16* g, u16* l) {
    __builtin_amdgcn_global_load_lds((const __attribute__((address_space(1))) void*)g,
                                     (__attribute__((address_space(3))) void*)l,
                                     16, 0, 0);
}

__device__ __forceinline__ void stc(u16* p, float v) { *p = f2b(v); }
__device__ __forceinline__ void stc(float* p, float v) { *p = v; }

// ---------------------------------------------------------------------------
// 1) InstanceNorm stats: one block per (b,d) row of 65536 fp32 elements.
// ---------------------------------------------------------------------------
__global__ __launch_bounds__(256) void stats_kernel(const float* __restrict__ x,
                                                    float* __restrict__ mu,
                                                    float* __restrict__ rstd) {
    int bd = blockIdx.x;                       // 0..511
    const float* row = x + (size_t)bd * P_LEN;
    int tid = threadIdx.x;
    float s = 0.f, sq = 0.f;
    for (int i = 0; i < P_LEN / (256 * 4); ++i) {
        int idx = (i * 256 + tid) * 4;
        float4 u = *(const float4*)(row + idx);
        s += u.x + u.y + u.z + u.w;
        sq += u.x * u.x + u.y * u.y + u.z * u.z + u.w * u.w;
    }
    for (int off = 32; off; off >>= 1) { s += __shfl_down(s, off); sq += __shfl_down(sq, off); }
    __shared__ float rs[4], rq[4];
    if ((tid & 63) == 0) { rs[tid >> 6] = s; rq[tid >> 6] = sq; }
    __syncthreads();
    if (tid == 0) {
        float S = rs[0] + rs[1] + rs[2] + rs[3];
        float Q = rq[0] + rq[1] + rq[2] + rq[3];
        float m = S * (1.f / 65536.f);
        float var = Q * (1.f / 65536.f) - m * m;
        mu[bd] = m;
        rstd[bd] = rsqrtf(var + 1e-5f);
    }
}

// ---------------------------------------------------------------------------
// 2) Fold norm into QKV weights (bf16) + bias correction (fp32).
// ---------------------------------------------------------------------------
__global__ __launch_bounds__(256) void fold_kernel(const float* __restrict__ in_w,
                                                   const float* __restrict__ in_b,
                                                   const float* __restrict__ mu,
                                                   const float* __restrict__ rstd,
                                                   u16* __restrict__ Wp,
                                                   float* __restrict__ bprime) {
    int bid = blockIdx.x;              // b*768 + e
    int b = bid / K3, e = bid % K3;
    int d = threadIdx.x;
    float w = in_w[e * D_MODEL + d];
    float r = rstd[b * D_MODEL + d];
    float m = mu[b * D_MODEL + d];
    Wp[(size_t)bid * D_MODEL + d] = f2b(w * r);
    float contrib = w * r * m;
    for (int off = 32; off; off >>= 1) contrib += __shfl_down(contrib, off);
    __shared__ float rr[4];
    if ((d & 63) == 0) rr[d >> 6] = contrib;
    __syncthreads();
    if (d == 0) bprime[bid] = in_b[e] - (rr[0] + rr[1] + rr[2] + rr[3]);
}

__global__ void cvt_w(const float* __restrict__ w, u16* __restrict__ o) {
    int i = blockIdx.x * 256 + threadIdx.x;
    o[i] = f2b(w[i]);
}

// ---------------------------------------------------------------------------
// 3) Transpose + bf16 convert: x[d][p] fp32 -> xt[p][d] bf16 (one batch).
//    64x64 tiles through LDS.
// ---------------------------------------------------------------------------
__global__ __launch_bounds__(256) void transpose_x(const float* __restrict__ x,
                                                   u16* __restrict__ xt) {
    __shared__ float tile[64][65];
    int p0 = blockIdx.x * 64;
    int d0 = blockIdx.y * 64;
    int tid = threadIdx.x;
    int dr = tid >> 4;            // 0..15
    int pc = (tid & 15) * 4;      // 0..60
#pragma unroll
    for (int it = 0; it < 4; ++it) {
        int d = it * 16 + dr;
        float4 v = *(const float4*)&x[(size_t)(d0 + d) * P_LEN + p0 + pc];
        tile[pc + 0][d] = v.x;
        tile[pc + 1][d] = v.y;
        tile[pc + 2][d] = v.z;
        tile[pc + 3][d] = v.w;
    }
    __syncthreads();
    int pr = tid >> 3;            // 0..31
    int dc = (tid & 7) * 8;       // 0..56
#pragma unroll
    for (int it = 0; it < 2; ++it) {
        int p = it * 32 + pr;
        ushort4 o0 = make_ushort4(f2b(tile[p][dc + 0]), f2b(tile[p][dc + 1]),
                                  f2b(tile[p][dc + 2]), f2b(tile[p][dc + 3]));
        ushort4 o1 = make_ushort4(f2b(tile[p][dc + 4]), f2b(tile[p][dc + 5]),
                                  f2b(tile[p][dc + 6]), f2b(tile[p][dc + 7]));
        u16* dst = xt + (size_t)(p0 + p) * D_MODEL + d0 + dc;
        *(ushort4*)dst = o0;
        *(ushort4*)(dst + 4) = o1;
    }
}

// ---------------------------------------------------------------------------
// 4) MFMA GEMM: C[M x 65536] = A[M x 256] * Bt[65536 x 256]^T (+bias,+resid)
//    A, Bt bf16 row-major (K contiguous). 128x128 tile, 4 waves, 4x4 MFMA
//    16x16x32 per wave. global_load_lds w/ XOR chunk swizzle (conflict-free
//    b128 fragment reads without LDS padding).
// ---------------------------------------------------------------------------
template <bool RESID, typename OT>
__global__ __launch_bounds__(256) void mgemm(const u16* __restrict__ A,
                                             const u16* __restrict__ Bt,
                                             const float* __restrict__ bias,
                                             const float* __restrict__ resid,
                                             OT* __restrict__ Cout) {
    __shared__ __align__(16) u16 As[128 * BK];   // [m][k] swizzled, 16 KB
    __shared__ __align__(16) u16 Bs[128 * BK];   // [n][k] swizzled, 16 KB
    const int tid  = threadIdx.x;
    const int wave = tid >> 6;
    const int lane = tid & 63;
    const int m0 = blockIdx.y * 128;
    const int p0 = blockIdx.x * 128;
    const int mw = (wave >> 1) * 64;
    const int nw = (wave & 1) * 64;

    floatx4 acc[4][4];
#pragma unroll
    for (int i = 0; i < 4; ++i)
#pragma unroll
        for (int j = 0; j < 4; ++j) acc[i][j] = (floatx4){0.f, 0.f, 0.f, 0.f};

    const int srow = lane >> 3;      // 0..7 (row within 8-row group)
    const int schunk = lane & 7;     // 0..7 (16B chunk within 128B row)
    const int q  = lane >> 4;        // quad 0..3
    const int rl = lane & 15;

    for (int s = 0; s < 4; ++s) {
        const int k0 = s * BK;
#pragma unroll
        for (int j = 0; j < 4; ++j) {
            int rbase = wave * 32 + j * 8;            // wave-uniform
            int r = rbase + srow;
            int cg = schunk ^ (r & 7);                // swizzle on global side
            gload_lds16(A  + ((size_t)(m0 + r) << 8) + k0 + cg * 8, &As[rbase * BK]);
            gload_lds16(Bt + ((size_t)(p0 + r) << 8) + k0 + cg * 8, &Bs[rbase * BK]);
        }
        __syncthreads();   // drains vmcnt before barrier (compiler-inserted)
#pragma unroll
        for (int ks = 0; ks < 2; ++ks) {
            bf16x8 af[4], bf[4];
#pragma unroll
            for (int ti = 0; ti < 4; ++ti) {
                int r = mw + 16 * ti + rl;
                int cp = (ks * 4 + q) ^ (r & 7);
                af[ti] = *(const bf16x8*)&As[r * BK + cp * 8];
            }
#pragma unroll
            for (int tj = 0; tj < 4; ++tj) {
                int r = nw + 16 * tj + rl;
                int cp = (ks * 4 + q) ^ (r & 7);
                bf[tj] = *(const bf16x8*)&Bs[r * BK + cp * 8];
            }
#pragma unroll
            for (int ti = 0; ti < 4; ++ti)
#pragma unroll
                for (int tj = 0; tj < 4; ++tj)
                    acc[ti][tj] = __builtin_amdgcn_mfma_f32_16x16x32_bf16(
                        af[ti], bf[tj], acc[ti][tj], 0, 0, 0);
        }
        __syncthreads();
    }

    // Epilogue. C/D layout: col = lane&15 (n), row = quad*4 + reg (m).
#pragma unroll
    for (int ti = 0; ti < 4; ++ti) {
#pragma unroll
        for (int i = 0; i < 4; ++i) {
            int e = m0 + mw + 16 * ti + 4 * q + i;
            float bv = bias[e];
            size_t rowbase = (size_t)e * P_LEN + p0 + nw;
#pragma unroll
            for (int tj = 0; tj < 4; ++tj) {
                size_t addr = rowbase + 16 * tj + rl;
                float v = acc[ti][tj][i] + bv;
                if (RESID) v += resid[addr];
                stc(Cout + addr, v);
            }
        }
    }
}

// ---------------------------------------------------------------------------
// 5) Attention per (c,h). qkv layout [768][65536] bf16 (unchanged reads).
//    Output now transposed: attT[p][256] bf16 (d contiguous) for mgemm2.
// ---------------------------------------------------------------------------
__global__ __launch_bounds__(256) void attn_k(const u16* __restrict__ qkv,
                                              u16* __restrict__ attT) {
    int bid = blockIdx.x;          // 0..511
    int c = bid >> 3, h = bid & 7;
    int tid = threadIdx.x;
    size_t colbase = (size_t)c * TDIM;
    const u16* qb = qkv + (size_t)(h * FDIM) * P_LEN + colbase;
    const u16* kb = qkv + (size_t)(D_MODEL + h * FDIM) * P_LEN + colbase;
    const u16* vb = qkv + (size_t)(2 * D_MODEL + h * FDIM) * P_LEN + colbase;

    __shared__ float kmax[32], kinv[32];
    __shared__ float ekt[32][65];
    __shared__ float vt[64][36];
    __shared__ float ctxs[32][36];

    int row = tid >> 3, g = tid & 7;
    const u16* krow = kb + (size_t)row * P_LEN;

    float m = -1e30f;
    for (int i = 0; i < 32; ++i) {
        ushort4 u = *(const ushort4*)(krow + g * 4 + i * 32);
        m = fmaxf(m, fmaxf(fmaxf(b2f(u.x), b2f(u.y)), fmaxf(b2f(u.z), b2f(u.w))));
    }
    for (int off = 4; off; off >>= 1) m = fmaxf(m, __shfl_down(m, off, 8));
    if (g == 0) kmax[row] = m;
    __syncthreads();
    float rm = kmax[row];
    float s = 0.f;
    for (int i = 0; i < 32; ++i) {
        ushort4 u = *(const ushort4*)(krow + g * 4 + i * 32);
        s += __expf(b2f(u.x) - rm) + __expf(b2f(u.y) - rm) +
             __expf(b2f(u.z) - rm) + __expf(b2f(u.w) - rm);
    }
    for (int off = 4; off; off >>= 1) s += __shfl_down(s, off, 8);
    if (g == 0) kinv[row] = 1.f / (s * (float)TDIM);
    __syncthreads();

    float mymax = kmax[row];
    float myinv = kinv[row];
    const u16* vrow = vb + (size_t)row * P_LEN;

    int kd = tid >> 3, vg = tid & 7;
    float cacc[4] = {0.f, 0.f, 0.f, 0.f};
    for (int tile = 0; tile < 16; ++tile) {
        int t0 = tile * 64;
        int col = g * 8;
        ushort4 u1 = *(const ushort4*)(krow + t0 + col);
        ushort4 u2 = *(const ushort4*)(krow + t0 + col + 4);
        ushort4 w1 = *(const ushort4*)(vrow + t0 + col);
        ushort4 w2 = *(const ushort4*)(vrow + t0 + col + 4);
        __syncthreads();
        ekt[row][col + 0] = __expf(b2f(u1.x) - mymax) * myinv;
        ekt[row][col + 1] = __expf(b2f(u1.y) - mymax) * myinv;
        ekt[row][col + 2] = __expf(b2f(u1.z) - mymax) * myinv;
        ekt[row][col + 3] = __expf(b2f(u1.w) - mymax) * myinv;
        ekt[row][col + 4] = __expf(b2f(u2.x) - mymax) * myinv;
        ekt[row][col + 5] = __expf(b2f(u2.y) - mymax) * myinv;
        ekt[row][col + 6] = __expf(b2f(u2.z) - mymax) * myinv;
        ekt[row][col + 7] = __expf(b2f(u2.w) - mymax) * myinv;
        vt[col + 0][row] = b2f(w1.x);
        vt[col + 1][row] = b2f(w1.y);
        vt[col + 2][row] = b2f(w1.z);
        vt[col + 3][row] = b2f(w1.w);
        vt[col + 4][row] = b2f(w2.x);
        vt[col + 5][row] = b2f(w2.y);
        vt[col + 6][row] = b2f(w2.z);
        vt[col + 7][row] = b2f(w2.w);
        __syncthreads();
#pragma unroll 16
        for (int t = 0; t < 64; ++t) {
            float e = ekt[kd][t];
            float4 v4 = *(const float4*)&vt[t][vg * 4];
            cacc[0] += e * v4.x;
            cacc[1] += e * v4.y;
            cacc[2] += e * v4.z;
            cacc[3] += e * v4.w;
        }
    }
    __syncthreads();
    const float scale = 0.17677669529663687f;   // 1/sqrt(32)
    ctxs[kd][vg * 4 + 0] = cacc[0] * scale;
    ctxs[kd][vg * 4 + 1] = cacc[1] * scale;
    ctxs[kd][vg * 4 + 2] = cacc[2] * scale;
    ctxs[kd][vg * 4 + 3] = cacc[3] * scale;
    __syncthreads();

    for (int pair = 0; pair < 2; ++pair) {
        int t1 = tid + pair * 512;
        int t2 = t1 + 256;
        float pa[32], pb[32];
        float ma = -1e30f, mb = -1e30f;
#pragma unroll
        for (int f = 0; f < 32; ++f) {
            pa[f] = b2f(qb[(size_t)f * P_LEN + t1]);
            pb[f] = b2f(qb[(size_t)f * P_LEN + t2]);
            ma = fmaxf(ma, pa[f]);
            mb = fmaxf(mb, pb[f]);
        }
        float sa = 0.f, sb = 0.f;
#pragma unroll
        for (int f = 0; f < 32; ++f) {
            pa[f] = __expf(pa[f] - ma); sa += pa[f];
            pb[f] = __expf(pb[f] - mb); sb += pb[f];
        }
        float ia = 1.f / sa, ib = 1.f / sb;
#pragma unroll
        for (int f = 0; f < 32; ++f) { pa[f] *= ia; pb[f] *= ib; }

        size_t r1 = (size_t)(colbase + t1) * D_MODEL + h * FDIM;
        size_t r2 = (size_t)(colbase + t2) * D_MODEL + h * FDIM;
        for (int vg2 = 0; vg2 < 8; ++vg2) {
            float4 a1 = {0.f, 0.f, 0.f, 0.f}, a2 = {0.f, 0.f, 0.f, 0.f};
#pragma unroll
            for (int kd2 = 0; kd2 < 32; ++kd2) {
                float4 c4 = *(const float4*)&ctxs[kd2][vg2 * 4];
                a1.x += pa[kd2] * c4.x; a1.y += pa[kd2] * c4.y;
                a1.z += pa[kd2] * c4.z; a1.w += pa[kd2] * c4.w;
                a2.x += pb[kd2] * c4.x; a2.y += pb[kd2] * c4.y;
                a2.z += pb[kd2] * c4.z; a2.w += pb[kd2] * c4.w;
            }
            *(ushort4*)&attT[r1 + vg2 * 4] =
                make_ushort4(f2b(a1.x), f2b(a1.y), f2b(a1.z), f2b(a1.w));
            *(ushort4*)&attT[r2 + vg2 * 4] =
                make_ushort4(f2b(a2.x), f2b(a2.y), f2b(a2.z), f2b(a2.w));
        }
    }
}

// ---------------------------------------------------------------------------
// Workspace layout (bytes):
//   mu      [512]  f32            @ 0
//   rstd    [512]  f32            @ 2048
//   Wp      [1536*256] bf16       @ 4096        (786432)
//   bprime  [1536] f32            @ 790528      (6144)
//   Wp2     [256*256]  bf16       @ 796672      (131072)
//   tbuf    [65536*256] bf16      @ 927744      (33554432)  xbT / attT (aliased)
//   qkvb    [768*65536] bf16      @ 34482176    (100663296) reused per batch
// total = 135145472 bytes (~135 MB)
// ---------------------------------------------------------------------------
extern "C" void kernel_launch(void* const* d_in, const int* in_sizes, int n_in,
                              void* d_out, int out_size, void* d_ws, size_t ws_size,
                              hipStream_t stream) {
    const float* x     = (const float*)d_in[0];
    const float* in_w  = (const float*)d_in[1];
    const float* in_b  = (const float*)d_in[2];
    const float* out_w = (const float*)d_in[3];
    const float* out_b = (const float*)d_in[4];
    float* out = (float*)d_out;

    char* ws = (char*)d_ws;
    float* mu     = (float*)(ws);
    float* rstd   = (float*)(ws + 2048);
    u16*   Wp     = (u16*)(ws + 4096);
    float* bprime = (float*)(ws + 790528);
    u16*   Wp2    = (u16*)(ws + 796672);
    u16*   tbuf   = (u16*)(ws + 927744);
    u16*   qkvb   = (u16*)(ws + 34482176);

    stats_kernel<<<512, 256, 0, stream>>>(x, mu, rstd);
    fold_kernel<<<1536, 256, 0, stream>>>(in_w, in_b, mu, rstd, Wp, bprime);
    cvt_w<<<256, 256, 0, stream>>>(out_w, Wp2);

    for (int b = 0; b < 2; ++b) {
        const float* xb = x + (size_t)b * D_MODEL * P_LEN;
        transpose_x<<<dim3(1024, 4), 256, 0, stream>>>(xb, tbuf);
        mgemm<false, u16><<<dim3(512, 6), 256, 0, stream>>>(
            Wp + (size_t)b * K3 * D_MODEL, tbuf, bprime + b * K3, nullptr, qkvb);
        attn_k<<<512, 256, 0, stream>>>(qkvb, tbuf);
        mgemm<true, float><<<dim3(512, 2), 256, 0, stream>>>(
            Wp2, tbuf, out_b, xb, out + (size_t)b * D_MODEL * P_LEN);
    }
}